// Round 5
// baseline (5520.687 us; speedup 1.0000x reference)
//
#include <hip/hip_runtime.h>
#include <hip/hip_bf16.h>

// Problem constants (S,B,D,H,T) = (4,512,256,1024,50)
#define S_ 4
#define B_ 512
#define D_ 256
#define H_ 1024
#define T_ 50
#define M_ (S_*B_)   // 2048 rows total

#define LDH (H_ + 8)   // padded LDS row stride for h1/h2 (bf16 elems)
#define LDU (D_ + 8)   // padded LDS row stride for u

// Per-stage weight stream: 192 chunks x 16KB = 3MB  (W1:0-31, W2:32-159, W3:160-191)
#define NCHK 192
#define CHKB 16384

typedef __attribute__((ext_vector_type(8))) __bf16 bf16x8;
typedef __attribute__((ext_vector_type(4))) float  f32x4;

#define MFMA16(a, b, c) __builtin_amdgcn_mfma_f32_16x16x32_bf16(a, b, c, 0, 0, 0)
#define SB0() __builtin_amdgcn_sched_barrier(0)
// chunk-landed wait: 2 younger chunks (4 loads) may stay in flight
#define VMW() do { asm volatile("s_waitcnt vmcnt(4)" ::: "memory"); SB0(); } while (0)
// counted ds-retire guard: N newest ds ops may stay outstanding; everything
// older (the pair whose ring slot the next DMA will overwrite) is retired.
#define GRD(n_) do { asm volatile("s_waitcnt lgkmcnt(" #n_ ")" ::: "memory"); SB0(); } while (0)
// layer barrier WITHOUT vmcnt drain (prefetch stays in flight across it)
#define LBAR() do { SB0(); asm volatile("s_waitcnt lgkmcnt(0)" ::: "memory"); \
                    __builtin_amdgcn_s_barrier(); SB0(); } while (0)

__device__ __forceinline__ void gld16(const void* g, void* l) {
  // async global->LDS, 16B per lane. LDS dest = wave-uniform base (+lane*16 by HW).
  __builtin_amdgcn_global_load_lds(
      (const __attribute__((address_space(1))) void*)g,
      (__attribute__((address_space(3))) void*)l, 16, 0, 0);
}

// NaN-free fast tanh: saturates to +/-1, ~1e-6 abs error (<< bf16 eps)
__device__ __forceinline__ float fast_tanh(float x) {
  const float e = __expf(2.f * x);
  return 1.f - 2.f / (e + 1.f);
}

// non-temporal output store (keep 100MB traj stream from evicting the 3MB
// cyclic weight working set out of the per-XCD L2s)
__device__ __forceinline__ void store_out(void* out, size_t off, float v,
                                          int ofl) {
  if (ofl) {
    __builtin_nontemporal_store(v, (float*)out + off);
  } else {
    const unsigned short u =
        __builtin_bit_cast(unsigned short, __float2bfloat16(v));
    __builtin_nontemporal_store(u, (unsigned short*)out + off);
  }
}

// ---------------------------------------------------------------------------
// Runtime dtype detection + dt table + reg_state zeros.
//   flags[0] = weights/first_point/output are f32 (1) or bf16 (0)
//   flags[1] = time grid is f32 (1) or bf16 (0)
// ---------------------------------------------------------------------------
__global__ void detect_k(const void* t_raw, const void* w2_raw,
                         float* dts, int* flags, void* out) {
  __shared__ int cnt;
  const int l = threadIdx.x;           // 64 threads, 1 block
  if (l == 0) cnt = 0;
  __syncthreads();
  const unsigned short* u = (const unsigned short*)w2_raw;
  int c = 0;
  #pragma unroll
  for (int j = 0; j < 4; ++j) {
    const unsigned short v = u[l * 4 + j];
    const unsigned e = (v >> 7) & 0xFF;          // bf16 exponent field
    if (e >= 128) c++;                            // |x| >= 2.0 or NaN/Inf
  }
  atomicAdd(&cnt, c);
  __syncthreads();
  const unsigned tw0 = *(const unsigned*)t_raw;
  const int t_is_f32 = (tw0 == 0u) ? 1 : 0;
  const int w_is_f32 = (cnt > 16) ? 1 : 0;
  if (l == 0) { flags[0] = w_is_f32; flags[1] = t_is_f32; }
  if (l < T_ - 1) {
    float t0, t1;
    if (t_is_f32) {
      const float* tf = (const float*)t_raw;
      t0 = tf[l]; t1 = tf[l + 1];
    } else {
      const __hip_bfloat16* tb = (const __hip_bfloat16*)t_raw;
      t0 = __bfloat162float(tb[l]); t1 = __bfloat162float(tb[l + 1]);
    }
    dts[l] = t1 - t0;
  }
  if (l < S_) {   // reg_state = 0
    const size_t ro = (size_t)M_ * T_ * D_ + l;
    if (w_is_f32) ((float*)out)[ro] = 0.f;
    else          ((__hip_bfloat16*)out)[ro] = __float2bfloat16(0.f);
  }
}

// ---------------------------------------------------------------------------
// transpose to bf16: dst[N][K] = bf16(src[K][N]); src dtype per flags[0]
// ---------------------------------------------------------------------------
__global__ void transpose_k(const void* __restrict__ src,
                            __hip_bfloat16* __restrict__ dst, int K, int N,
                            const int* __restrict__ flags) {
  __shared__ __hip_bfloat16 tile[32][33];
  const int f32 = flags[0];
  const int tx = threadIdx.x, ty = threadIdx.y;
  const int nb = blockIdx.x * 32, kb = blockIdx.y * 32;
  #pragma unroll
  for (int j = 0; j < 32; j += 8) {
    const size_t si = (size_t)(kb + ty + j) * N + nb + tx;
    tile[ty + j][tx] = f32 ? __float2bfloat16(((const float*)src)[si])
                           : ((const __hip_bfloat16*)src)[si];
  }
  __syncthreads();
  #pragma unroll
  for (int j = 0; j < 32; j += 8)
    dst[(size_t)(nb + ty + j) * K + kb + tx] = tile[tx][ty + j];
}

// ---------------------------------------------------------------------------
// biases -> fp32 workspace arrays
// ---------------------------------------------------------------------------
__global__ void prep_bias_k(const void* b1r, const void* b2r, const void* b3r,
                            float* bf1, float* bf2, float* bf3,
                            const int* flags) {
  const int i = blockIdx.x * 256 + threadIdx.x;   // H_ threads
  const int f32 = flags[0];
  bf1[i] = f32 ? ((const float*)b1r)[i]
               : __bfloat162float(((const __hip_bfloat16*)b1r)[i]);
  bf2[i] = f32 ? ((const float*)b2r)[i]
               : __bfloat162float(((const __hip_bfloat16*)b2r)[i]);
  if (i < D_)
    bf3[i] = f32 ? ((const float*)b3r)[i]
                 : __bfloat162float(((const __hip_bfloat16*)b3r)[i]);
}

// ---------------------------------------------------------------------------
// pack Wt[N][K] (row-major bf16) into 16KB-chunk, WAVE-PRIVATE fragment stream.
// frag idx = c*1024 + w*128 + ntl*64 + lane  (16B per frag), ntl in {0,1}:
//   TPW==8 (L1/L2): chunk c -> kk = c>>2, tile nt = (c&3)*2 + ntl
//   TPW==2 (L3):    chunk c -> kk = c,    tile nt = ntl
// Fragment content (MFMA B layout), elems j of lane:
//   Wt[(w*TPW+nt)*16 + (lane&15)][kk*32 + (lane>>4)*8 + j]
// Wave w consumes exactly bytes [c*16K + w*2K, +2K) -- the same bytes wave w
// DMAs, so producer==consumer and no block barriers are needed.
// ---------------------------------------------------------------------------
__global__ void pack_k(const __hip_bfloat16* __restrict__ Wt,
                       __hip_bfloat16* __restrict__ P, int K, int TPW) {
  const int frag = blockIdx.x * 256 + threadIdx.x;   // one 16B fragment each
  const int lane = frag & 63;
  const int c    = frag >> 10;
  const int q    = frag & 1023;
  const int w    = q >> 7;
  const int ntl  = (q >> 6) & 1;
  int kk, nt;
  if (TPW == 8) { kk = c >> 2; nt = (c & 3) * 2 + ntl; }
  else          { kk = c;      nt = ntl; }
  const int n  = (w * TPW + nt) * 16 + (lane & 15);
  const int ko = kk * 32 + (lane >> 4) * 8;
  *(bf16x8*)&P[(size_t)frag * 8] = *(const bf16x8*)&Wt[(size_t)n * K + ko];
}

// ---------------------------------------------------------------------------
// Persistent ODE kernel: 128 blocks x 16 rows, 512 threads (8 waves).
// Chunk pipeline, 1-chunk-skewed: at step nc we (a) vmcnt-wait chunk nc,
// (b) ds_read it into incoming regs, (c) counted-lgkm guard (prev step's
// reads retired -> DMA target slot safe), (d) issue DMA nc+3, (e) MFMA the
// PREVIOUS chunk's regs (LDS latency hidden under a full step). No lgkmcnt(0)
// in the steady state; 3 no-drain barriers per stage.
// LDS 137KB -> 1 block/CU; 8 waves = 2/SIMD.
// ---------------------------------------------------------------------------
__global__ __launch_bounds__(512, 2) void ode_k(
    const void* __restrict__ fp_raw,
    const __hip_bfloat16* __restrict__ Wall,   // packed [W1|W2|W3], 3MB
    const float* __restrict__ bf1, const float* __restrict__ bf2,
    const float* __restrict__ bf3, const float* __restrict__ dts,
    const int* __restrict__ flags, void* __restrict__ out) {
  __shared__ __hip_bfloat16 uA[16 * LDU];       //  8.2 KB
  __shared__ __hip_bfloat16 h1s[16 * LDH];      // 32.3 KB
  __shared__ __hip_bfloat16 h2s[16 * LDH];      // 32.3 KB
  __shared__ __hip_bfloat16 Bst[4 * 8192];      // 64   KB ring (4 x 16KB)

  const int tid = threadIdx.x;
  const int wave = tid >> 6, lane = tid & 63;
  const int l16 = lane & 15, quad = lane >> 4;
  const int m0 = blockIdx.x * 16;
  const int rb = quad * 4;                 // this lane's C-layout row base
  const int ofl = flags[0];

  // stream pointers (wave-private 2KB per 16KB chunk)
  const char* gw = (const char*)Wall + wave * 2048 + (size_t)lane * 16; // per-lane
  char* lb = (char*)Bst + wave * 2048;                 // wave-uniform DMA dest
  const char* bS = (const char*)Bst + wave * 2048 + (size_t)lane * 16;  // reads

  auto iss = [&](int tc) {                 // issue chunk tc (0..191), 2KB/wave
    const char* g_ = gw + (size_t)tc * CHKB;
    char* l_ = lb + (tc & 3) * CHKB;
    gld16(g_, l_);
    gld16(g_ + 1024, l_ + 1024);
  };
  #define LDR(slot_, half_) \
    (*(const bf16x8*)(bS + (slot_) * CHKB + (half_) * 1024))

  // pipelined step: consume prev chunk (pb), read this chunk into nb, refill.
  #define STEP(slot_, issc_, g_, acc0_, acc1_, aF_)                 \
    do {                                                            \
      VMW();                                                        \
      bf16x8 nb0 = LDR(slot_, 0), nb1 = LDR(slot_, 1);              \
      GRD(g_);                                                      \
      iss(issc_);                                                   \
      acc0_ = MFMA16(aF_, pb0, acc0_);                              \
      acc1_ = MFMA16(aF_, pb1, acc1_);                              \
      pb0 = nb0; pb1 = nb1;                                         \
    } while (0)

  // bias registers (match epilogue column mapping)
  float b1r[8], b2r[8], b3r[2];
  #pragma unroll
  for (int nt = 0; nt < 8; nt++) {
    b1r[nt] = bf1[wave * 128 + nt * 16 + l16];
    b2r[nt] = bf2[wave * 128 + nt * 16 + l16];
  }
  #pragma unroll
  for (int nt = 0; nt < 2; nt++) b3r[nt] = bf3[wave * 32 + nt * 16 + l16];

  // RK4 state in registers at this lane's L3 C-layout positions:
  //   (m = m0 + rb + r, d = wave*32 + nt*16 + l16)
  float yreg[2][4], ab[2][4];
  #pragma unroll
  for (int nt = 0; nt < 2; nt++) {
    const int d = wave * 32 + nt * 16 + l16;
    #pragma unroll
    for (int r = 0; r < 4; r++) {
      const int m = m0 + rb + r;
      const size_t si = (size_t)m * D_ + d;
      const float v = ofl ? ((const float*)fp_raw)[si]
                          : __bfloat162float(((const __hip_bfloat16*)fp_raw)[si]);
      yreg[nt][r] = v;
      ab[nt][r] = 0.f;
      uA[(rb + r) * LDU + d] = __float2bfloat16(v);   // stage0 u = y
      store_out(out, ((size_t)m * T_) * D_ + d, v, ofl);  // traj[t=0] = y
    }
  }
  // prime the ring: chunks 0,1,2 in flight (6 loads)
  iss(0); iss(1); iss(2);
  LBAR();

  #pragma unroll 1
  for (int t = 0; t < T_ - 1; ++t) {
    const float dtv = dts[t];
    #pragma unroll 1
    for (int st4 = 0; st4 < 4; ++st4) {
      // ---- L1: h1 = tanh(u @ W1 + b1), K=256, chunks 0..31 ----
      {
        f32x4 acc[8];
        #pragma unroll
        for (int i = 0; i < 8; i++) acc[i] = f32x4{0.f, 0.f, 0.f, 0.f};
        bf16x8 pb0, pb1, aC;
        // prime chunk 0 (slot 0)
        VMW(); pb0 = LDR(0, 0); pb1 = LDR(0, 1); GRD(2); iss(3);
        aC = *(const bf16x8*)&uA[l16 * LDU + quad * 8];
        STEP(1, 4, 3, acc[0], acc[1], aC);
        STEP(2, 5, 2, acc[2], acc[3], aC);
        STEP(3, 6, 2, acc[4], acc[5], aC);
        #pragma unroll 1
        for (int kk = 1; kk < 8; ++kk) {
          const int nc = 4 * kk;
          // step0: drain prev group's pos3 with prev aF
          VMW();
          { bf16x8 nb0 = LDR(0, 0), nb1 = LDR(0, 1);
            GRD(2); iss(nc + 3);
            acc[6] = MFMA16(aC, pb0, acc[6]);
            acc[7] = MFMA16(aC, pb1, acc[7]);
            pb0 = nb0; pb1 = nb1; }
          aC = *(const bf16x8*)&uA[l16 * LDU + kk * 32 + quad * 8];
          STEP(1, nc + 4, 3, acc[0], acc[1], aC);
          STEP(2, nc + 5, 2, acc[2], acc[3], aC);
          STEP(3, nc + 6, 2, acc[4], acc[5], aC);
        }
        acc[6] = MFMA16(aC, pb0, acc[6]);   // final drain
        acc[7] = MFMA16(aC, pb1, acc[7]);
        #pragma unroll
        for (int nt = 0; nt < 8; nt++) {
          const int col = wave * 128 + nt * 16 + l16;
          #pragma unroll
          for (int r = 0; r < 4; r++)
            h1s[(rb + r) * LDH + col] =
                __float2bfloat16(fast_tanh(acc[nt][r] + b1r[nt]));
        }
      }
      LBAR();
      // ---- L2: h2 = tanh(h1 @ W2 + b2), K=1024, chunks 32..159 ----
      {
        f32x4 acc[8];
        #pragma unroll
        for (int i = 0; i < 8; i++) acc[i] = f32x4{0.f, 0.f, 0.f, 0.f};
        bf16x8 pb0, pb1, aC;
        // prime chunk 32 (slot 0)
        VMW(); pb0 = LDR(0, 0); pb1 = LDR(0, 1); GRD(2); iss(35);
        aC = *(const bf16x8*)&h1s[l16 * LDH + quad * 8];
        STEP(1, 36, 3, acc[0], acc[1], aC);
        STEP(2, 37, 2, acc[2], acc[3], aC);
        STEP(3, 38, 2, acc[4], acc[5], aC);
        #pragma unroll 1
        for (int kk = 1; kk < 32; ++kk) {
          const int nc = 32 + 4 * kk;
          VMW();
          { bf16x8 nb0 = LDR(0, 0), nb1 = LDR(0, 1);
            GRD(2); iss(nc + 3);
            acc[6] = MFMA16(aC, pb0, acc[6]);
            acc[7] = MFMA16(aC, pb1, acc[7]);
            pb0 = nb0; pb1 = nb1; }
          aC = *(const bf16x8*)&h1s[l16 * LDH + kk * 32 + quad * 8];
          STEP(1, nc + 4, 3, acc[0], acc[1], aC);
          STEP(2, nc + 5, 2, acc[2], acc[3], aC);
          STEP(3, nc + 6, 2, acc[4], acc[5], aC);
        }
        acc[6] = MFMA16(aC, pb0, acc[6]);
        acc[7] = MFMA16(aC, pb1, acc[7]);
        #pragma unroll
        for (int nt = 0; nt < 8; nt++) {
          const int col = wave * 128 + nt * 16 + l16;
          #pragma unroll
          for (int r = 0; r < 4; r++)
            h2s[(rb + r) * LDH + col] =
                __float2bfloat16(fast_tanh(acc[nt][r] + b2r[nt]));
        }
      }
      LBAR();
      // ---- L3: k = h2 @ W3 + b3, K=1024, chunks 160..191 (kk = chunk) ----
      {
        f32x4 k0 = f32x4{0.f, 0.f, 0.f, 0.f};
        f32x4 k1 = f32x4{0.f, 0.f, 0.f, 0.f};
        bf16x8 pb0, pb1, aP;
        // prime chunk 160 (slot 0)
        VMW(); pb0 = LDR(0, 0); pb1 = LDR(0, 1); GRD(2); iss(163);
        aP = *(const bf16x8*)&h2s[l16 * LDH + quad * 8];
        #pragma unroll 1
        for (int c = 1; c < 32; ++c) {
          VMW();
          { bf16x8 nb0 = LDR(c & 3, 0), nb1 = LDR(c & 3, 1);
            GRD(3);
            int tc = 163 + c; if (tc >= NCHK) tc -= NCHK;
            iss(tc);
            k0 = MFMA16(aP, pb0, k0);
            k1 = MFMA16(aP, pb1, k1);
            pb0 = nb0; pb1 = nb1; }
          aP = *(const bf16x8*)&h2s[l16 * LDH + c * 32 + quad * 8];
        }
        k0 = MFMA16(aP, pb0, k0);           // final drain
        k1 = MFMA16(aP, pb1, k1);
        // RK4 bookkeeping in registers + traj store + next-u build
        #pragma unroll
        for (int nt = 0; nt < 2; nt++) {
          const int d = wave * 32 + nt * 16 + l16;
          const f32x4 kacc = nt ? k1 : k0;
          #pragma unroll
          for (int r = 0; r < 4; r++) {
            const float kv = kacc[r] + b3r[nt];
            float uv;
            if (st4 == 0) {
              ab[nt][r] = kv;            uv = yreg[nt][r] + 0.5f * dtv * kv;
            } else if (st4 == 1) {
              ab[nt][r] += 2.f * kv;     uv = yreg[nt][r] + 0.5f * dtv * kv;
            } else if (st4 == 2) {
              ab[nt][r] += 2.f * kv;     uv = yreg[nt][r] + dtv * kv;
            } else {
              const float yn =
                  yreg[nt][r] + (dtv * (1.f / 6.f)) * (ab[nt][r] + kv);
              yreg[nt][r] = yn;
              uv = yn;                   // next timestep stage0: u = y
              store_out(out, ((size_t)(m0 + rb + r) * T_ + (t + 1)) * D_ + d,
                        yn, ofl);
            }
            uA[(rb + r) * LDU + d] = __float2bfloat16(uv);
          }
        }
      }
      LBAR();
    }
  }
  // drain dangling tail prefetches before LDS dealloc
  asm volatile("s_waitcnt vmcnt(0)" ::: "memory");
  #undef STEP
  #undef LDR
}

// ---------------------------------------------------------------------------
extern "C" void kernel_launch(void* const* d_in, const int* in_sizes, int n_in,
                              void* d_out, int out_size, void* d_ws, size_t ws_size,
                              hipStream_t stream) {
  const void* fp   = d_in[0];
  const void* tarr = d_in[1];
  const void* W1   = d_in[2];
  const void* b1   = d_in[3];
  const void* W2   = d_in[4];
  const void* b2   = d_in[5];
  const void* W3   = d_in[6];
  const void* b3   = d_in[7];

  // workspace carve (~6.2 MB total, all bases 16B-aligned).
  // W1p|W2p|W3p MUST stay contiguous in this order: they form the 3MB
  // per-stage chunk stream [chunks 0..31 | 32..159 | 160..191].
  char* ws = (char*)d_ws;
  __hip_bfloat16* W1p = (__hip_bfloat16*)ws; ws += (size_t)H_ * D_ * 2;
  __hip_bfloat16* W2p = (__hip_bfloat16*)ws; ws += (size_t)H_ * H_ * 2;
  __hip_bfloat16* W3p = (__hip_bfloat16*)ws; ws += (size_t)D_ * H_ * 2;
  __hip_bfloat16* W1t = (__hip_bfloat16*)ws; ws += (size_t)H_ * D_ * 2;
  __hip_bfloat16* W2t = (__hip_bfloat16*)ws; ws += (size_t)H_ * H_ * 2;
  __hip_bfloat16* W3t = (__hip_bfloat16*)ws; ws += (size_t)D_ * H_ * 2;
  float* bf1  = (float*)ws;                  ws += (size_t)H_ * 4;
  float* bf2  = (float*)ws;                  ws += (size_t)H_ * 4;
  float* bf3  = (float*)ws;                  ws += (size_t)D_ * 4;
  float* dts  = (float*)ws;                  ws += 64 * 4;
  int*   flags= (int*)ws;                    ws += 64 * 4;

  detect_k<<<1, 64, 0, stream>>>(tarr, W2, dts, flags, d_out);
  dim3 tb(32, 8);
  transpose_k<<<dim3(H_ / 32, D_ / 32), tb, 0, stream>>>(W1, W1t, D_, H_, flags);
  transpose_k<<<dim3(H_ / 32, H_ / 32), tb, 0, stream>>>(W2, W2t, H_, H_, flags);
  transpose_k<<<dim3(D_ / 32, H_ / 32), tb, 0, stream>>>(W3, W3t, H_, D_, flags);
  prep_bias_k<<<H_ / 256, 256, 0, stream>>>(b1, b2, b3, bf1, bf2, bf3, flags);
  pack_k<<<(H_ * D_ / 8) / 256, 256, 0, stream>>>(W1t, W1p, D_, 8);
  pack_k<<<(H_ * H_ / 8) / 256, 256, 0, stream>>>(W2t, W2p, H_, 8);
  pack_k<<<(D_ * H_ / 8) / 256, 256, 0, stream>>>(W3t, W3p, H_, 2);
  ode_k<<<M_ / 16, 512, 0, stream>>>(fp, W1p, bf1, bf2, bf3, dts, flags, d_out);
}

// Round 6
// 4917.862 us; speedup vs baseline: 1.1226x; 1.1226x over previous
//
#include <hip/hip_runtime.h>
#include <hip/hip_bf16.h>

// Problem constants (S,B,D,H,T) = (4,512,256,1024,50)
#define S_ 4
#define B_ 512
#define D_ 256
#define H_ 1024
#define T_ 50
#define M_ (S_*B_)   // 2048 rows total

#define LDH (H_ + 8)   // padded LDS row stride for h1/h2 (bf16 elems)
#define LDU (D_ + 8)   // padded LDS row stride for u

// Per-stage weight stream: 192 chunks x 16KB = 3MB  (W1:0-31, W2:32-159, W3:160-191)
#define NCHK 192
#define CHKB 16384

typedef __attribute__((ext_vector_type(8))) __bf16 bf16x8;
typedef __attribute__((ext_vector_type(4))) float  f32x4;

#define MFMA16(a, b, c) __builtin_amdgcn_mfma_f32_16x16x32_bf16(a, b, c, 0, 0, 0)
#define SB0() __builtin_amdgcn_sched_barrier(0)
// chunk-landed wait: 6 younger chunks (12 loads) may stay in flight.
// SB0 after the wait pins the following MFMAs behind it (guide rule #18).
#define VMW() do { asm volatile("s_waitcnt vmcnt(12)" ::: "memory"); SB0(); } while (0)
// layer barrier WITHOUT vmcnt drain (register prefetch stays in flight)
#define LBAR() do { SB0(); asm volatile("s_waitcnt lgkmcnt(0)" ::: "memory"); \
                    __builtin_amdgcn_s_barrier(); SB0(); } while (0)

// Two B-fragments (one chunk's per-wave slice halves) global -> VGPR, direct
// in MFMA layout. Early-clobber keeps dests disjoint from the address pair.
__device__ __forceinline__ void ld2(bf16x8& r0, bf16x8& r1, const void* p) {
  asm volatile("global_load_dwordx4 %0, %2, off\n\t"
               "global_load_dwordx4 %1, %2, off offset:1024"
               : "=&v"(r0), "=&v"(r1) : "v"(p) : "memory");
}

// NaN-free fast tanh: saturates to +/-1, ~1e-6 abs error (<< bf16 eps)
__device__ __forceinline__ float fast_tanh(float x) {
  const float e = __expf(2.f * x);
  return 1.f - 2.f / (e + 1.f);
}

// non-temporal output store (keep 100MB traj stream from evicting the 3MB
// cyclic weight working set out of the per-XCD L2s)
__device__ __forceinline__ void store_out(void* out, size_t off, float v,
                                          int ofl) {
  if (ofl) {
    __builtin_nontemporal_store(v, (float*)out + off);
  } else {
    const unsigned short u =
        __builtin_bit_cast(unsigned short, __float2bfloat16(v));
    __builtin_nontemporal_store(u, (unsigned short*)out + off);
  }
}

// ---------------------------------------------------------------------------
// Runtime dtype detection + dt table + reg_state zeros.
//   flags[0] = weights/first_point/output are f32 (1) or bf16 (0)
//   flags[1] = time grid is f32 (1) or bf16 (0)
// ---------------------------------------------------------------------------
__global__ void detect_k(const void* t_raw, const void* w2_raw,
                         float* dts, int* flags, void* out) {
  __shared__ int cnt;
  const int l = threadIdx.x;           // 64 threads, 1 block
  if (l == 0) cnt = 0;
  __syncthreads();
  const unsigned short* u = (const unsigned short*)w2_raw;
  int c = 0;
  #pragma unroll
  for (int j = 0; j < 4; ++j) {
    const unsigned short v = u[l * 4 + j];
    const unsigned e = (v >> 7) & 0xFF;          // bf16 exponent field
    if (e >= 128) c++;                            // |x| >= 2.0 or NaN/Inf
  }
  atomicAdd(&cnt, c);
  __syncthreads();
  const unsigned tw0 = *(const unsigned*)t_raw;
  const int t_is_f32 = (tw0 == 0u) ? 1 : 0;
  const int w_is_f32 = (cnt > 16) ? 1 : 0;
  if (l == 0) { flags[0] = w_is_f32; flags[1] = t_is_f32; }
  if (l < T_ - 1) {
    float t0, t1;
    if (t_is_f32) {
      const float* tf = (const float*)t_raw;
      t0 = tf[l]; t1 = tf[l + 1];
    } else {
      const __hip_bfloat16* tb = (const __hip_bfloat16*)t_raw;
      t0 = __bfloat162float(tb[l]); t1 = __bfloat162float(tb[l + 1]);
    }
    dts[l] = t1 - t0;
  }
  if (l < S_) {   // reg_state = 0
    const size_t ro = (size_t)M_ * T_ * D_ + l;
    if (w_is_f32) ((float*)out)[ro] = 0.f;
    else          ((__hip_bfloat16*)out)[ro] = __float2bfloat16(0.f);
  }
}

// ---------------------------------------------------------------------------
// transpose to bf16: dst[N][K] = bf16(src[K][N]); src dtype per flags[0]
// ---------------------------------------------------------------------------
__global__ void transpose_k(const void* __restrict__ src,
                            __hip_bfloat16* __restrict__ dst, int K, int N,
                            const int* __restrict__ flags) {
  __shared__ __hip_bfloat16 tile[32][33];
  const int f32 = flags[0];
  const int tx = threadIdx.x, ty = threadIdx.y;
  const int nb = blockIdx.x * 32, kb = blockIdx.y * 32;
  #pragma unroll
  for (int j = 0; j < 32; j += 8) {
    const size_t si = (size_t)(kb + ty + j) * N + nb + tx;
    tile[ty + j][tx] = f32 ? __float2bfloat16(((const float*)src)[si])
                           : ((const __hip_bfloat16*)src)[si];
  }
  __syncthreads();
  #pragma unroll
  for (int j = 0; j < 32; j += 8)
    dst[(size_t)(nb + ty + j) * K + kb + tx] = tile[tx][ty + j];
}

// ---------------------------------------------------------------------------
// biases -> fp32 workspace arrays
// ---------------------------------------------------------------------------
__global__ void prep_bias_k(const void* b1r, const void* b2r, const void* b3r,
                            float* bf1, float* bf2, float* bf3,
                            const int* flags) {
  const int i = blockIdx.x * 256 + threadIdx.x;   // H_ threads
  const int f32 = flags[0];
  bf1[i] = f32 ? ((const float*)b1r)[i]
               : __bfloat162float(((const __hip_bfloat16*)b1r)[i]);
  bf2[i] = f32 ? ((const float*)b2r)[i]
               : __bfloat162float(((const __hip_bfloat16*)b2r)[i]);
  if (i < D_)
    bf3[i] = f32 ? ((const float*)b3r)[i]
                 : __bfloat162float(((const __hip_bfloat16*)b3r)[i]);
}

// ---------------------------------------------------------------------------
// pack Wt[N][K] (row-major bf16) into 16KB-chunk, WAVE-PRIVATE fragment stream.
// frag idx = c*1024 + w*128 + ntl*64 + lane  (16B per frag), ntl in {0,1}:
//   TPW==8 (L1/L2): chunk c -> kk = c>>2, tile nt = (c&3)*2 + ntl
//   TPW==2 (L3):    chunk c -> kk = c,    tile nt = ntl
// Fragment content (MFMA B layout), elems j of lane:
//   Wt[(w*TPW+nt)*16 + (lane&15)][kk*32 + (lane>>4)*8 + j]
// Wave w's slice of chunk c is bytes [c*16K + w*2K, +2K); each LANE's 2x16B
// live at +lane*16 and +1024+lane*16 -> direct per-lane register loads.
// ---------------------------------------------------------------------------
__global__ void pack_k(const __hip_bfloat16* __restrict__ Wt,
                       __hip_bfloat16* __restrict__ P, int K, int TPW) {
  const int frag = blockIdx.x * 256 + threadIdx.x;   // one 16B fragment each
  const int lane = frag & 63;
  const int c    = frag >> 10;
  const int q    = frag & 1023;
  const int w    = q >> 7;
  const int ntl  = (q >> 6) & 1;
  int kk, nt;
  if (TPW == 8) { kk = c >> 2; nt = (c & 3) * 2 + ntl; }
  else          { kk = c;      nt = ntl; }
  const int n  = (w * TPW + nt) * 16 + (lane & 15);
  const int ko = kk * 32 + (lane >> 4) * 8;
  *(bf16x8*)&P[(size_t)frag * 8] = *(const bf16x8*)&Wt[(size_t)n * K + ko];
}

// ---------------------------------------------------------------------------
// Persistent ODE kernel: 128 blocks x 16 rows, 512 threads (8 waves).
// B-weights stream DIRECTLY global->VGPR through an 8-slot register ring
// (64 VGPRs/lane) with counted vmcnt(12): 7 chunks (14KB/wave) in flight.
// No LDS for B at all. A-fragments in LDS with 1-group register skew.
// 3 no-drain barriers per stage (layer boundaries only).
// LDS ~83KB (u/h1/h2 + guard) -> 1 block/CU; 8 waves = 2/SIMD.
// ---------------------------------------------------------------------------
__global__ __launch_bounds__(512, 2) void ode_k(
    const void* __restrict__ fp_raw,
    const __hip_bfloat16* __restrict__ Wall,   // packed [W1|W2|W3], 3MB
    const float* __restrict__ bf1, const float* __restrict__ bf2,
    const float* __restrict__ bf3, const float* __restrict__ dts,
    const int* __restrict__ flags, void* __restrict__ out) {
  __shared__ __hip_bfloat16 uA[16 * LDU];       //  8.4 KB
  __shared__ __hip_bfloat16 h1s[16 * LDH];      // 32.3 KB
  __shared__ __hip_bfloat16 h2s[16 * LDH];      // 32.3 KB
  __shared__ float lds_guard[2048];             //  8   KB -> >80KB: 1 block/CU

  const int tid = threadIdx.x;
  const int wave = tid >> 6, lane = tid & 63;
  const int l16 = lane & 15, quad = lane >> 4;
  const int m0 = blockIdx.x * 16;
  const int rb = quad * 4;                 // this lane's C-layout row base
  const int ofl = flags[0];
  if (ofl == 31337)                        // never true; keeps lds_guard live
    ((volatile float*)lds_guard)[tid & 2047] = 1.f;

  // per-lane global base of this wave's slice within each chunk
  const char* gw = (const char*)Wall + wave * 2048 + (size_t)lane * 16;

  // 8-slot register ring for B fragments (slot = chunk & 7; 192 % 8 == 0)
  bf16x8 rb0[8], rb1[8];

  // chunk step: wait chunk c landed; 2 MFMAs consume slot c&7; refill slot
  // (c+7)&7 with chunk (c+7)%192. Ring slot indices are compile-time in all
  // unrolled bodies. WAR on the refilled slot is 7 chunks (~1800cyc) old.
  #define BSTEP(c_, a_, acc0_, acc1_)                                     \
    do {                                                                  \
      VMW();                                                              \
      acc0_ = MFMA16(a_, rb0[(c_) & 7], acc0_);                           \
      acc1_ = MFMA16(a_, rb1[(c_) & 7], acc1_);                           \
      SB0();                                                              \
      { int tc_ = (c_) + 7; if (tc_ >= NCHK) tc_ -= NCHK;                 \
        ld2(rb0[((c_) + 7) & 7], rb1[((c_) + 7) & 7],                     \
            gw + (size_t)tc_ * CHKB); }                                   \
    } while (0)

  // bias registers (match epilogue column mapping)
  float b1r[8], b2r[8], b3r[2];
  #pragma unroll
  for (int nt = 0; nt < 8; nt++) {
    b1r[nt] = bf1[wave * 128 + nt * 16 + l16];
    b2r[nt] = bf2[wave * 128 + nt * 16 + l16];
  }
  #pragma unroll
  for (int nt = 0; nt < 2; nt++) b3r[nt] = bf3[wave * 32 + nt * 16 + l16];

  // RK4 state in registers at this lane's L3 C-layout positions:
  //   (m = m0 + rb + r, d = wave*32 + nt*16 + l16)
  float yreg[2][4], ab[2][4];
  #pragma unroll
  for (int nt = 0; nt < 2; nt++) {
    const int d = wave * 32 + nt * 16 + l16;
    #pragma unroll
    for (int r = 0; r < 4; r++) {
      const int m = m0 + rb + r;
      const size_t si = (size_t)m * D_ + d;
      const float v = ofl ? ((const float*)fp_raw)[si]
                          : __bfloat162float(((const __hip_bfloat16*)fp_raw)[si]);
      yreg[nt][r] = v;
      ab[nt][r] = 0.f;
      uA[(rb + r) * LDU + d] = __float2bfloat16(v);   // stage0 u = y
      store_out(out, ((size_t)m * T_) * D_ + d, v, ofl);  // traj[t=0] = y
    }
  }
  // prime the register ring: chunks 0..6 in flight (14 loads)
  #pragma unroll
  for (int c = 0; c < 7; ++c)
    ld2(rb0[c], rb1[c], gw + (size_t)c * CHKB);
  LBAR();

  #pragma unroll 1
  for (int t = 0; t < T_ - 1; ++t) {
    const float dtv = dts[t];
    #pragma unroll 1
    for (int st4 = 0; st4 < 4; ++st4) {
      // ---- L1: h1 = tanh(u @ W1 + b1), K=256, chunks 0..31 ----
      {
        f32x4 acc[8];
        #pragma unroll
        for (int i = 0; i < 8; i++) acc[i] = f32x4{0.f, 0.f, 0.f, 0.f};
        bf16x8 aF = *(const bf16x8*)&uA[l16 * LDU + quad * 8];
        #pragma unroll
        for (int kk = 0; kk < 8; ++kk) {
          const int kn = (kk + 1 < 8) ? (kk + 1) : 0;   // clamped prefetch
          const bf16x8 aN =
              *(const bf16x8*)&uA[l16 * LDU + kn * 32 + quad * 8];
          const int c0 = kk * 4;
          BSTEP(c0 + 0, aF, acc[0], acc[1]);
          BSTEP(c0 + 1, aF, acc[2], acc[3]);
          BSTEP(c0 + 2, aF, acc[4], acc[5]);
          BSTEP(c0 + 3, aF, acc[6], acc[7]);
          aF = aN;
        }
        #pragma unroll
        for (int nt = 0; nt < 8; nt++) {
          const int col = wave * 128 + nt * 16 + l16;
          #pragma unroll
          for (int r = 0; r < 4; r++)
            h1s[(rb + r) * LDH + col] =
                __float2bfloat16(fast_tanh(acc[nt][r] + b1r[nt]));
        }
      }
      LBAR();
      // ---- L2: h2 = tanh(h1 @ W2 + b2), K=1024, chunks 32..159 ----
      {
        f32x4 acc[8];
        #pragma unroll
        for (int i = 0; i < 8; i++) acc[i] = f32x4{0.f, 0.f, 0.f, 0.f};
        bf16x8 aF = *(const bf16x8*)&h1s[l16 * LDH + quad * 8];
        #pragma unroll 1
        for (int g = 0; g < 16; ++g) {     // 8 chunks per g (slots 0..7)
          const int kk0 = 2 * g;
          const bf16x8 aN1 =
              *(const bf16x8*)&h1s[l16 * LDH + (kk0 + 1) * 32 + quad * 8];
          const int c0 = 32 + 8 * g;
          BSTEP(c0 + 0, aF, acc[0], acc[1]);
          BSTEP(c0 + 1, aF, acc[2], acc[3]);
          BSTEP(c0 + 2, aF, acc[4], acc[5]);
          BSTEP(c0 + 3, aF, acc[6], acc[7]);
          aF = aN1;
          const int kn = (kk0 + 2 < 32) ? (kk0 + 2) : 0;  // clamped prefetch
          const bf16x8 aN2 =
              *(const bf16x8*)&h1s[l16 * LDH + kn * 32 + quad * 8];
          BSTEP(c0 + 4, aF, acc[0], acc[1]);
          BSTEP(c0 + 5, aF, acc[2], acc[3]);
          BSTEP(c0 + 6, aF, acc[4], acc[5]);
          BSTEP(c0 + 7, aF, acc[6], acc[7]);
          aF = aN2;
        }
        #pragma unroll
        for (int nt = 0; nt < 8; nt++) {
          const int col = wave * 128 + nt * 16 + l16;
          #pragma unroll
          for (int r = 0; r < 4; r++)
            h2s[(rb + r) * LDH + col] =
                __float2bfloat16(fast_tanh(acc[nt][r] + b2r[nt]));
        }
      }
      LBAR();
      // ---- L3: k = h2 @ W3 + b3, K=1024, chunks 160..191 (kk = c-160) ----
      {
        f32x4 k0 = f32x4{0.f, 0.f, 0.f, 0.f};
        f32x4 k1 = f32x4{0.f, 0.f, 0.f, 0.f};
        bf16x8 aF = *(const bf16x8*)&h2s[l16 * LDH + quad * 8];
        #pragma unroll 1
        for (int g = 0; g < 4; ++g) {      // 8 chunks per g (slots 0..7)
          const int c0 = 160 + 8 * g;
          #pragma unroll
          for (int i = 0; i < 8; ++i) {
            const int kk = 8 * g + i;
            const int kn = (kk + 1 < 32) ? (kk + 1) : 0;  // clamped prefetch
            const bf16x8 aN =
                *(const bf16x8*)&h2s[l16 * LDH + kn * 32 + quad * 8];
            BSTEP(c0 + i, aF, k0, k1);
            aF = aN;
          }
        }
        // RK4 bookkeeping in registers + traj store + next-u build
        #pragma unroll
        for (int nt = 0; nt < 2; nt++) {
          const int d = wave * 32 + nt * 16 + l16;
          const f32x4 kacc = nt ? k1 : k0;
          #pragma unroll
          for (int r = 0; r < 4; r++) {
            const float kv = kacc[r] + b3r[nt];
            float uv;
            if (st4 == 0) {
              ab[nt][r] = kv;            uv = yreg[nt][r] + 0.5f * dtv * kv;
            } else if (st4 == 1) {
              ab[nt][r] += 2.f * kv;     uv = yreg[nt][r] + 0.5f * dtv * kv;
            } else if (st4 == 2) {
              ab[nt][r] += 2.f * kv;     uv = yreg[nt][r] + dtv * kv;
            } else {
              const float yn =
                  yreg[nt][r] + (dtv * (1.f / 6.f)) * (ab[nt][r] + kv);
              yreg[nt][r] = yn;
              uv = yn;                   // next timestep stage0: u = y
              store_out(out, ((size_t)(m0 + rb + r) * T_ + (t + 1)) * D_ + d,
                        yn, ofl);
            }
            uA[(rb + r) * LDU + d] = __float2bfloat16(uv);
          }
        }
      }
      LBAR();
    }
  }
  asm volatile("s_waitcnt vmcnt(0)" ::: "memory");  // retire dangling prefetch
  #undef BSTEP
}

// ---------------------------------------------------------------------------
extern "C" void kernel_launch(void* const* d_in, const int* in_sizes, int n_in,
                              void* d_out, int out_size, void* d_ws, size_t ws_size,
                              hipStream_t stream) {
  const void* fp   = d_in[0];
  const void* tarr = d_in[1];
  const void* W1   = d_in[2];
  const void* b1   = d_in[3];
  const void* W2   = d_in[4];
  const void* b2   = d_in[5];
  const void* W3   = d_in[6];
  const void* b3   = d_in[7];

  // workspace carve (~6.2 MB total, all bases 16B-aligned).
  // W1p|W2p|W3p MUST stay contiguous in this order: they form the 3MB
  // per-stage chunk stream [chunks 0..31 | 32..159 | 160..191].
  char* ws = (char*)d_ws;
  __hip_bfloat16* W1p = (__hip_bfloat16*)ws; ws += (size_t)H_ * D_ * 2;
  __hip_bfloat16* W2p = (__hip_bfloat16*)ws; ws += (size_t)H_ * H_ * 2;
  __hip_bfloat16* W3p = (__hip_bfloat16*)ws; ws += (size_t)D_ * H_ * 2;
  __hip_bfloat16* W1t = (__hip_bfloat16*)ws; ws += (size_t)H_ * D_ * 2;
  __hip_bfloat16* W2t = (__hip_bfloat16*)ws; ws += (size_t)H_ * H_ * 2;
  __hip_bfloat16* W3t = (__hip_bfloat16*)ws; ws += (size_t)D_ * H_ * 2;
  float* bf1  = (float*)ws;                  ws += (size_t)H_ * 4;
  float* bf2  = (float*)ws;                  ws += (size_t)H_ * 4;
  float* bf3  = (float*)ws;                  ws += (size_t)D_ * 4;
  float* dts  = (float*)ws;                  ws += 64 * 4;
  int*   flags= (int*)ws;                    ws += 64 * 4;

  detect_k<<<1, 64, 0, stream>>>(tarr, W2, dts, flags, d_out);
  dim3 tb(32, 8);
  transpose_k<<<dim3(H_ / 32, D_ / 32), tb, 0, stream>>>(W1, W1t, D_, H_, flags);
  transpose_k<<<dim3(H_ / 32, H_ / 32), tb, 0, stream>>>(W2, W2t, H_, H_, flags);
  transpose_k<<<dim3(D_ / 32, H_ / 32), tb, 0, stream>>>(W3, W3t, H_, D_, flags);
  prep_bias_k<<<H_ / 256, 256, 0, stream>>>(b1, b2, b3, bf1, bf2, bf3, flags);
  pack_k<<<(H_ * D_ / 8) / 256, 256, 0, stream>>>(W1t, W1p, D_, 8);
  pack_k<<<(H_ * H_ / 8) / 256, 256, 0, stream>>>(W2t, W2p, H_, 8);
  pack_k<<<(D_ * H_ / 8) / 256, 256, 0, stream>>>(W3t, W3p, H_, 2);
  ode_k<<<M_ / 16, 512, 0, stream>>>(fp, W1p, bf1, bf2, bf3, dts, flags, d_out);
}